// Round 4
// baseline (639.841 us; speedup 1.0000x reference)
//
#include <hip/hip_runtime.h>
#include <hip/hip_bf16.h>

// Geometry (fixed): B=1, C=8, D=H=W=128.
constexpr int HW2 = 16384;
constexpr int DHW = 2097152;

// MFMA staging: LDS cell = 8 ci (bf16, 16 B) at (g = dz*3+dy group, xi).
constexpr int PKG = 13;   // groups per xi row (9 used + 3 K-pad + 1 pitch pad)
constexpr int XT  = 130;  // staged x extent: x = -1 .. 128

typedef short bf16x8 __attribute__((ext_vector_type(8)));  // 8 bf16 = 4 VGPR
typedef float f32x4  __attribute__((ext_vector_type(4)));

__device__ inline unsigned short f2b(float f) {
  __hip_bfloat16 h = __float2bfloat16(f);
  return *(unsigned short*)&h;
}
__device__ inline float b2f(unsigned short u) {
  __hip_bfloat16 h = *(__hip_bfloat16*)&u;
  return __bfloat162float(h);
}

// ---------------------------------------------------------------------------
// Prep: pack w1/w2 into MFMA A-fragment order, bf16, dx-split.
// Extra tail zero-fills the 32-B x-window guard regions around ti/xi so
// edge-tap garbage reads are finite (their weights are zeroed in k_adapt3).
// ---------------------------------------------------------------------------
__global__ __launch_bounds__(256) void k_prep(
    const float* __restrict__ w1, const float* __restrict__ w2,
    unsigned short* __restrict__ Wpack2, unsigned short* __restrict__ Wpack1,
    float* __restrict__ g_ti, float* __restrict__ g_xi) {
  int i = blockIdx.x * 256 + threadIdx.x;
  if (i < 9216) {
    int j = i & 7;
    int lane = (i >> 3) & 63;
    int Mt = (i >> 9) & 1;
    int g2 = i >> 10;         // dx*3 + s
    int s = g2 % 3, dx = g2 / 3;
    int oc = Mt * 16 + (lane & 15);
    int kr = s * 32 + (lane >> 4) * 8 + j;
    int ci = kr & 7, g = kr >> 3;
    float w = 0.f;
    if (oc < 27 && g < 9) {
      int dzr = g / 3, dyr = g % 3;
      w = w2[(oc * 8 + ci) * 27 + dzr * 9 + dyr * 3 + dx];
    }
    Wpack2[i] = f2b(w);
  }
  int jj = i - 9216;
  if (jj >= 0 && jj < 4608) {
    int j = jj & 7;
    int lane = (jj >> 3) & 63;
    int g2 = jj >> 9;         // dx*3 + s
    int s = g2 % 3, dx = g2 / 3;
    int oc = lane & 15;
    int kr = s * 32 + (lane >> 4) * 8 + j;
    int ci = kr & 7, g = kr >> 3;
    float w = 0.f;
    if (oc < 8 && g < 9) {
      int dzr = g / 3, dyr = g % 3;
      w = w1[(oc * 8 + ci) * 27 + dzr * 9 + dyr * 3 + dx];
    }
    Wpack1[jj] = f2b(w);
  }
  int gg = i - 13824;
  if (gg >= 0 && gg < 32) {
    float* p = (gg < 8)  ? (g_ti - 8 + gg)
             : (gg < 16) ? (g_ti + (size_t)8 * DHW + (gg - 8))
             : (gg < 24) ? (g_xi - 8 + (gg - 16))
                         : (g_xi + (size_t)8 * DHW + (gg - 24));
    *p = 0.f;
  }
}

// ---------------------------------------------------------------------------
// Transpose x: [ci][z][y][x] fp32 -> [z][y][x][ci] bf16 (xb, for conv1 MFMA)
//                                 and [z][y][x][ci] fp32 (xi, for adapt pass)
// ---------------------------------------------------------------------------
__global__ __launch_bounds__(256) void k_xpose(
    const float* __restrict__ x, unsigned short* __restrict__ xb,
    float* __restrict__ xi) {
  int idx = blockIdx.x * 256 + threadIdx.x;  // voxel
  float f[8];
  unsigned v[4];
#pragma unroll
  for (int p = 0; p < 4; ++p) {
    f[2 * p]     = x[(size_t)(2 * p) * DHW + idx];
    f[2 * p + 1] = x[(size_t)(2 * p + 1) * DHW + idx];
    unsigned lo = f2b(f[2 * p]);
    unsigned hi = f2b(f[2 * p + 1]);
    v[p] = lo | (hi << 16);
  }
  ((uint4*)xb)[idx] = make_uint4(v[0], v[1], v[2], v[3]);
  float4* xo = (float4*)(xi + (size_t)idx * 8);
  xo[0] = make_float4(f[0], f[1], f[2], f[3]);
  xo[1] = make_float4(f[4], f[5], f[6], f[7]);
}

// ---------------------------------------------------------------------------
// Kernel 1: conv3d(x, w1) + bias + ReLU (8 -> 8), implicit-GEMM MFMA.
// ---------------------------------------------------------------------------
__global__ __launch_bounds__(256) void k_conv1m(
    const unsigned short* __restrict__ xb,
    const unsigned short* __restrict__ Wpack1,
    const float* __restrict__ b1, unsigned short* __restrict__ hb) {
  __shared__ __align__(16) unsigned short T[XT * PKG * 8];
  const int tid  = threadIdx.x;
  const int lane = tid & 63;
  const int wv   = tid >> 6;
  const int z0 = blockIdx.x >> 7;
  const int y0 = blockIdx.x & 127;

  bf16x8 wf[3][3];
  {
    const bf16x8* wp = (const bf16x8*)Wpack1;
#pragma unroll
    for (int dx = 0; dx < 3; ++dx)
#pragma unroll
      for (int s = 0; s < 3; ++s)
        wf[dx][s] = wp[(dx * 3 + s) * 64 + lane];
  }

  const uint4* src = (const uint4*)xb;
  uint4* dst = (uint4*)T;
#pragma unroll 1
  for (int c = tid; c < 12 * XT; c += 256) {
    int g  = c / XT;          // 0..11
    int xi = c - g * XT;
    uint4 v = make_uint4(0u, 0u, 0u, 0u);
    if (g < 9) {
      int z = z0 + g / 3 - 1, y = y0 + g % 3 - 1, xg = xi - 1;
      if ((unsigned)z < 128u && (unsigned)y < 128u && (unsigned)xg < 128u)
        v = src[(z * 128 + y) * 128 + xg];
    }
    dst[xi * PKG + g] = v;
  }
  __syncthreads();

  f32x4 acc[2];
#pragma unroll
  for (int nt = 0; nt < 2; ++nt) acc[nt] = (f32x4){0.f, 0.f, 0.f, 0.f};

  const int n = lane & 15;
  const int q = lane >> 4;
  const int xbase = wv * 32 + n;

#pragma unroll
  for (int dx = 0; dx < 3; ++dx) {
#pragma unroll
    for (int s = 0; s < 3; ++s) {
      bf16x8 bfr[2];
#pragma unroll
      for (int nt = 0; nt < 2; ++nt) {
        int off = ((xbase + nt * 16 + dx) * PKG + (s * 4 + q)) * 8;
        bfr[nt] = *(const bf16x8*)&T[off];
      }
#pragma unroll
      for (int nt = 0; nt < 2; ++nt)
        acc[nt] = __builtin_amdgcn_mfma_f32_16x16x32_bf16(
            wf[dx][s], bfr[nt], acc[nt], 0, 0, 0);
    }
  }

  const int voxrow = (z0 * 128 + y0) * 128;
  if (q < 2) {
#pragma unroll
    for (int nt = 0; nt < 2; ++nt) {
      const int vox = voxrow + wv * 32 + nt * 16 + n;
      ushort4 o;
      o.x = f2b(fmaxf(acc[nt][0] + b1[q * 4 + 0], 0.f));
      o.y = f2b(fmaxf(acc[nt][1] + b1[q * 4 + 1], 0.f));
      o.z = f2b(fmaxf(acc[nt][2] + b1[q * 4 + 2], 0.f));
      o.w = f2b(fmaxf(acc[nt][3] + b1[q * 4 + 3], 0.f));
      *(ushort4*)(hb + (size_t)vox * 8 + q * 4) = o;
    }
  }
}

// ---------------------------------------------------------------------------
// Kernel 2: conv3d(h, w2) (8 -> 27) + fused L1 norm, implicit-GEMM MFMA.
// ---------------------------------------------------------------------------
__global__ __launch_bounds__(256) void k_conv2(
    const unsigned short* __restrict__ hb,
    const unsigned short* __restrict__ Wpack2,
    unsigned short* __restrict__ wn) {
  __shared__ __align__(16) unsigned short T[XT * PKG * 8];
  const int tid  = threadIdx.x;
  const int lane = tid & 63;
  const int wv   = tid >> 6;
  const int z0 = blockIdx.x >> 7;
  const int y0 = blockIdx.x & 127;

  bf16x8 wf[3][3][2];
  {
    const bf16x8* wp = (const bf16x8*)Wpack2;
#pragma unroll
    for (int dx = 0; dx < 3; ++dx)
#pragma unroll
      for (int s = 0; s < 3; ++s)
#pragma unroll
        for (int mt = 0; mt < 2; ++mt)
          wf[dx][s][mt] = wp[((dx * 3 + s) * 2 + mt) * 64 + lane];
  }

  const uint4* src = (const uint4*)hb;
  uint4* dst = (uint4*)T;
#pragma unroll 1
  for (int c = tid; c < 12 * XT; c += 256) {
    int g  = c / XT;
    int xi = c - g * XT;
    uint4 v = make_uint4(0u, 0u, 0u, 0u);
    if (g < 9) {
      int z = z0 + g / 3 - 1, y = y0 + g % 3 - 1, xg = xi - 1;
      if ((unsigned)z < 128u && (unsigned)y < 128u && (unsigned)xg < 128u)
        v = src[(z * 128 + y) * 128 + xg];
    }
    dst[xi * PKG + g] = v;
  }
  __syncthreads();

  f32x4 acc[2][2];  // [nt][mt]
#pragma unroll
  for (int nt = 0; nt < 2; ++nt)
#pragma unroll
    for (int mt = 0; mt < 2; ++mt) acc[nt][mt] = (f32x4){0.f, 0.f, 0.f, 0.f};

  const int n = lane & 15;
  const int q = lane >> 4;
  const int xbase = wv * 32 + n;

#pragma unroll
  for (int dx = 0; dx < 3; ++dx) {
#pragma unroll
    for (int s = 0; s < 3; ++s) {
      bf16x8 bfr[2];
#pragma unroll
      for (int nt = 0; nt < 2; ++nt) {
        int off = ((xbase + nt * 16 + dx) * PKG + (s * 4 + q)) * 8;
        bfr[nt] = *(const bf16x8*)&T[off];
      }
#pragma unroll
      for (int mt = 0; mt < 2; ++mt)
#pragma unroll
        for (int nt = 0; nt < 2; ++nt)
          acc[nt][mt] = __builtin_amdgcn_mfma_f32_16x16x32_bf16(
              wf[dx][s][mt], bfr[nt], acc[nt][mt], 0, 0, 0);
    }
  }

  const int voxrow = (z0 * 128 + y0) * 128;
#pragma unroll
  for (int nt = 0; nt < 2; ++nt) {
    float ns = 0.f;
#pragma unroll
    for (int r = 0; r < 4; ++r) ns += fabsf(acc[nt][0][r]);
#pragma unroll
    for (int r = 0; r < 4; ++r) {
      int oc = 16 + q * 4 + r;
      ns += (oc < 27) ? fabsf(acc[nt][1][r]) : 0.f;
    }
    ns += __shfl_xor(ns, 16);
    ns += __shfl_xor(ns, 32);
    float sc = 1.f / fmaxf(ns, 1e-12f);
    const int vox = voxrow + wv * 32 + nt * 16 + n;
#pragma unroll
    for (int r = 0; r < 4; ++r) {
      int oc = q * 4 + r;
      wn[(size_t)oc * DHW + vox] = f2b(acc[nt][0][r] * sc);
    }
#pragma unroll
    for (int r = 0; r < 4; ++r) {
      int oc = 16 + q * 4 + r;
      if (oc < 27)
        wn[(size_t)oc * DHW + vox] = f2b(acc[nt][1][r] * sc);
    }
  }
}

// ---------------------------------------------------------------------------
// Kernel 3: adaptive 3x3x3 conv, interleaved fp32 in [vox][8]; planar bf16 wn.
// R3 post-mortem: unroll-1 loop compiled to 56 VGPR -> ~2 outstanding loads
// -> 13.5k cycles/group (serial latency). Fix: explicit register DOUBLE-
// BUFFER: prefetch group g+1 (12 b128 X + 3 ushort4 w) into named B set
// while computing group g from A set. Manually 2x-unrolled steady loop keeps
// all indexing static (no scratch). __launch_bounds__(256,3): cap 168 VGPR,
// live set ~152, occupancy 3 waves/SIMD (same as measured R3) but ~15
// outstanding loads/wave instead of ~2.
// Middle passes keep the R3 LDS store transpose (WRITE_SIZE 64 MiB, proven).
// ---------------------------------------------------------------------------
#define PREFETCH(g_, XA_, XB_, WV_, vld_)                              \
  {                                                                    \
    const int dz_ = (g_) / 3 - 1, dy_ = (g_) % 3 - 1;                  \
    const int zz_ = z + dz_, yy_ = y + dy_;                            \
    vld_ = ((unsigned)zz_ < 128u) & ((unsigned)yy_ < 128u);            \
    const int rowi_ = vld_ ? (zz_ * 128 + yy_) : rest;                 \
    const float* rb_ = inx + (size_t)rowi_ * 1024;                     \
    _Pragma("unroll")                                                  \
    for (int p = 0; p < 6; ++p) {                                      \
      XA_[p] = *(const f32x4*)(rb_ + p * 8);                           \
      XB_[p] = *(const f32x4*)(rb_ + p * 8 + 4);                       \
    }                                                                  \
    WV_[0] = *(const ushort4*)(wpg);                                   \
    WV_[1] = *(const ushort4*)(wpg + DHW);                             \
    WV_[2] = *(const ushort4*)(wpg + 2 * DHW);                         \
    wpg += 3 * (size_t)DHW;                                            \
  }

#define COMPUTE(XA_, XB_, WV_, vld_)                                   \
  {                                                                    \
    float wt[3][4];                                                    \
    _Pragma("unroll")                                                  \
    for (int dxi = 0; dxi < 3; ++dxi) {                                \
      wt[dxi][0] = vld_ ? b2f(WV_[dxi].x) : 0.f;                       \
      wt[dxi][1] = vld_ ? b2f(WV_[dxi].y) : 0.f;                       \
      wt[dxi][2] = vld_ ? b2f(WV_[dxi].z) : 0.f;                       \
      wt[dxi][3] = vld_ ? b2f(WV_[dxi].w) : 0.f;                       \
    }                                                                  \
    wt[0][0] = (xg == 0) ? 0.f : wt[0][0];                             \
    wt[2][3] = (xg == 124) ? 0.f : wt[2][3];                           \
    _Pragma("unroll")                                                  \
    for (int dxi = 0; dxi < 3; ++dxi) {                                \
      _Pragma("unroll")                                                \
      for (int v = 0; v < 4; ++v) {                                    \
        const float w_ = wt[dxi][v];                                   \
        _Pragma("unroll")                                              \
        for (int c = 0; c < 4; ++c) {                                  \
          accA[v][c] = fmaf(XA_[v + dxi][c], w_, accA[v][c]);          \
          accB[v][c] = fmaf(XB_[v + dxi][c], w_, accB[v][c]);          \
        }                                                              \
      }                                                                \
    }                                                                  \
  }

template <int FINAL>
__global__ __launch_bounds__(256, 3) void k_adapt3(
    const float* __restrict__ in, const unsigned short* __restrict__ wn,
    float* __restrict__ out) {
  __shared__ __align__(16) float S[4096];  // 16 KiB
  const int tid = threadIdx.x;
  const int t = blockIdx.x * 256 + tid;
  const int xg = (t & 31) * 4;
  const int rest = t >> 5;        // z*128 + y
  const int y = rest & 127;
  const int z = rest >> 7;
  const int vox0 = rest * 128 + xg;

  f32x4 accA[4], accB[4];  // accA[v] = ch 0..3, accB[v] = ch 4..7
#pragma unroll
  for (int v = 0; v < 4; ++v) {
    accA[v] = (f32x4){0.f, 0.f, 0.f, 0.f};
    accB[v] = (f32x4){0.f, 0.f, 0.f, 0.f};
  }

  const float* inx = in + (size_t)xg * 8 - 8;      // x window base (x = xg-1)
  const unsigned short* wpg = wn + vox0;           // tap ptr, += 3*DHW per g

  bool vA, vB;
  f32x4 XA0[6], XB0[6], XA1[6], XB1[6];
  ushort4 WA[3], WB[3];

  PREFETCH(0, XA0, XB0, WA, vA);
#pragma unroll 1
  for (int i = 0; i < 4; ++i) {
    const int g = 2 * i;
    PREFETCH(g + 1, XA1, XB1, WB, vB);
    COMPUTE(XA0, XB0, WA, vA);
    PREFETCH(g + 2, XA0, XB0, WA, vA);
    COMPUTE(XA1, XB1, WB, vB);
  }
  COMPUTE(XA0, XB0, WA, vA);  // g = 8

  if (FINAL) {
    // planar fp32 [c][vox] -> d_out
#pragma unroll
    for (int c = 0; c < 4; ++c) {
      f32x4 o = {accA[0][c], accA[1][c], accA[2][c], accA[3][c]};
      *(f32x4*)(out + (size_t)c * DHW + vox0) = o;
      f32x4 o2 = {accB[0][c], accB[1][c], accB[2][c], accB[3][c]};
      *(f32x4*)(out + (size_t)(c + 4) * DHW + vox0) = o2;
    }
  } else {
    // interleaved fp32 [vox][8] via two-phase LDS transpose.
    // Block owns 32 KiB contiguous at out + blockIdx*8192 floats.
    const int row = tid >> 5;   // 0..7 (local y-ish row)
    const int col = tid & 31;   // x-group
    const size_t base = (size_t)blockIdx.x * 8192;  // floats
#pragma unroll
    for (int h = 0; h < 2; ++h) {
      __syncthreads();
      if ((row >> 2) == h) {
        const int lo = (row & 3) * 4096 + col * 128;  // bytes in phase
#pragma unroll
        for (int k = 0; k < 8; ++k) {
          int off = lo + k * 16;
          int swz = off ^ (((off >> 7) & 7) << 4);
          f32x4 val = (k & 1) ? accB[k >> 1] : accA[k >> 1];
          *(f32x4*)((char*)S + swz) = val;
        }
      }
      __syncthreads();
#pragma unroll
      for (int k = 0; k < 4; ++k) {
        int off = k * 4096 + tid * 16;  // bytes in phase, lane-contiguous
        int swz = off ^ (((off >> 7) & 7) << 4);
        f32x4 v = *(const f32x4*)((char*)S + swz);
        *(f32x4*)(out + base + h * 4096 + (off >> 2)) = v;
      }
    }
  }
}

// ---------------------------------------------------------------------------
extern "C" void kernel_launch(void* const* d_in, const int* in_sizes, int n_in,
                              void* d_out, int out_size, void* d_ws, size_t ws_size,
                              hipStream_t stream) {
  const float* x  = (const float*)d_in[0];
  const float* w1 = (const float*)d_in[1];
  const float* b1 = (const float*)d_in[2];
  const float* w2 = (const float*)d_in[3];
  float* out = (float*)d_out;

  // Workspace (~236 MiB + pads):
  //   [0,   64M): xb(32M)+hb(32M) bf16; reused as ti = ws+256 (64M fp32)
  //   [64M+4K, 172M+4K): wn bf16 planar (27 x DHW)
  //   [172M+12K, 236M+12K): xi fp32 interleaved
  //   then Wpack2, Wpack1. 256-B/4-KiB pads double as x-window guards
  //   (zero-filled by k_prep tail).
  char* ws = (char*)d_ws;
  unsigned short* xb = (unsigned short*)ws;
  unsigned short* hb = (unsigned short*)(ws + (size_t)8 * DHW * 2);
  float* ti = (float*)(ws + 256);  // aliases xb+hb (both dead before adapt)
  unsigned short* wn = (unsigned short*)(ws + (size_t)16 * DHW * 2 + 4096);
  float* xi = (float*)(ws + (size_t)16 * DHW * 2 + 4096 +
                       (size_t)27 * DHW * 2 + 8192);
  unsigned short* Wpack2 =
      (unsigned short*)((char*)xi + (size_t)8 * DHW * 4 + 16384);
  unsigned short* Wpack1 = Wpack2 + 9216;

  dim3 blk(256);
  k_prep<<<55, blk, 0, stream>>>(w1, w2, Wpack2, Wpack1, ti, xi);
  k_xpose<<<DHW / 256, blk, 0, stream>>>(x, xb, xi);
  k_conv1m<<<128 * 128, blk, 0, stream>>>(xb, Wpack1, b1, hb);
  k_conv2<<<128 * 128, blk, 0, stream>>>(hb, Wpack2, wn);
  // adaptive ping-pong on interleaved fp32: xi -> ti -> xi -> out (planar)
  k_adapt3<0><<<DHW / 4 / 256, blk, 0, stream>>>(xi, wn, ti);
  k_adapt3<0><<<DHW / 4 / 256, blk, 0, stream>>>(ti, wn, xi);
  k_adapt3<1><<<DHW / 4 / 256, blk, 0, stream>>>(xi, wn, out);
}

// Round 5
// 418.034 us; speedup vs baseline: 1.5306x; 1.5306x over previous
//
#include <hip/hip_runtime.h>
#include <hip/hip_bf16.h>

// Geometry (fixed): B=1, C=8, D=H=W=128.
constexpr int HW2 = 16384;
constexpr int DHW = 2097152;

// MFMA staging: LDS cell = 8 ci (bf16, 16 B) at (g = dz*3+dy group, xi).
constexpr int PKG = 13;   // groups per xi row (9 used + 3 K-pad + 1 pitch pad)
constexpr int XT  = 130;  // staged x extent: x = -1 .. 128

typedef short bf16x8 __attribute__((ext_vector_type(8)));  // 8 bf16 = 4 VGPR
typedef float f32x4  __attribute__((ext_vector_type(4)));

__device__ inline unsigned short f2b(float f) {
  __hip_bfloat16 h = __float2bfloat16(f);
  return *(unsigned short*)&h;
}
__device__ inline float b2f(unsigned short u) {
  __hip_bfloat16 h = *(__hip_bfloat16*)&u;
  return __bfloat162float(h);
}

// ---------------------------------------------------------------------------
// Prep: pack w1/w2 into MFMA A-fragment order, bf16, dx-split.
// (Guard-zero tail kept from R3 — harmless.)
// ---------------------------------------------------------------------------
__global__ __launch_bounds__(256) void k_prep(
    const float* __restrict__ w1, const float* __restrict__ w2,
    unsigned short* __restrict__ Wpack2, unsigned short* __restrict__ Wpack1,
    float* __restrict__ g_ti, float* __restrict__ g_xi) {
  int i = blockIdx.x * 256 + threadIdx.x;
  if (i < 9216) {
    int j = i & 7;
    int lane = (i >> 3) & 63;
    int Mt = (i >> 9) & 1;
    int g2 = i >> 10;         // dx*3 + s
    int s = g2 % 3, dx = g2 / 3;
    int oc = Mt * 16 + (lane & 15);
    int kr = s * 32 + (lane >> 4) * 8 + j;
    int ci = kr & 7, g = kr >> 3;
    float w = 0.f;
    if (oc < 27 && g < 9) {
      int dzr = g / 3, dyr = g % 3;
      w = w2[(oc * 8 + ci) * 27 + dzr * 9 + dyr * 3 + dx];
    }
    Wpack2[i] = f2b(w);
  }
  int jj = i - 9216;
  if (jj >= 0 && jj < 4608) {
    int j = jj & 7;
    int lane = (jj >> 3) & 63;
    int g2 = jj >> 9;         // dx*3 + s
    int s = g2 % 3, dx = g2 / 3;
    int oc = lane & 15;
    int kr = s * 32 + (lane >> 4) * 8 + j;
    int ci = kr & 7, g = kr >> 3;
    float w = 0.f;
    if (oc < 8 && g < 9) {
      int dzr = g / 3, dyr = g % 3;
      w = w1[(oc * 8 + ci) * 27 + dzr * 9 + dyr * 3 + dx];
    }
    Wpack1[jj] = f2b(w);
  }
  int gg = i - 13824;
  if (gg >= 0 && gg < 32) {
    float* p = (gg < 8)  ? (g_ti - 8 + gg)
             : (gg < 16) ? (g_ti + (size_t)8 * DHW + (gg - 8))
             : (gg < 24) ? (g_xi - 8 + (gg - 16))
                         : (g_xi + (size_t)8 * DHW + (gg - 24));
    *p = 0.f;
  }
}

// ---------------------------------------------------------------------------
// Transpose x: [ci][z][y][x] fp32 -> [z][y][x][ci] bf16 (xb, for conv1 MFMA)
//                                 and [z][y][x][ci] fp32 (xi, for adapt pass)
// ---------------------------------------------------------------------------
__global__ __launch_bounds__(256) void k_xpose(
    const float* __restrict__ x, unsigned short* __restrict__ xb,
    float* __restrict__ xi) {
  int idx = blockIdx.x * 256 + threadIdx.x;  // voxel
  float f[8];
  unsigned v[4];
#pragma unroll
  for (int p = 0; p < 4; ++p) {
    f[2 * p]     = x[(size_t)(2 * p) * DHW + idx];
    f[2 * p + 1] = x[(size_t)(2 * p + 1) * DHW + idx];
    unsigned lo = f2b(f[2 * p]);
    unsigned hi = f2b(f[2 * p + 1]);
    v[p] = lo | (hi << 16);
  }
  ((uint4*)xb)[idx] = make_uint4(v[0], v[1], v[2], v[3]);
  float4* xo = (float4*)(xi + (size_t)idx * 8);
  xo[0] = make_float4(f[0], f[1], f[2], f[3]);
  xo[1] = make_float4(f[4], f[5], f[6], f[7]);
}

// ---------------------------------------------------------------------------
// Kernel 1: conv3d(x, w1) + bias + ReLU (8 -> 8), implicit-GEMM MFMA.
// ---------------------------------------------------------------------------
__global__ __launch_bounds__(256) void k_conv1m(
    const unsigned short* __restrict__ xb,
    const unsigned short* __restrict__ Wpack1,
    const float* __restrict__ b1, unsigned short* __restrict__ hb) {
  __shared__ __align__(16) unsigned short T[XT * PKG * 8];
  const int tid  = threadIdx.x;
  const int lane = tid & 63;
  const int wv   = tid >> 6;
  const int z0 = blockIdx.x >> 7;
  const int y0 = blockIdx.x & 127;

  bf16x8 wf[3][3];
  {
    const bf16x8* wp = (const bf16x8*)Wpack1;
#pragma unroll
    for (int dx = 0; dx < 3; ++dx)
#pragma unroll
      for (int s = 0; s < 3; ++s)
        wf[dx][s] = wp[(dx * 3 + s) * 64 + lane];
  }

  const uint4* src = (const uint4*)xb;
  uint4* dst = (uint4*)T;
#pragma unroll 1
  for (int c = tid; c < 12 * XT; c += 256) {
    int g  = c / XT;          // 0..11
    int xi = c - g * XT;
    uint4 v = make_uint4(0u, 0u, 0u, 0u);
    if (g < 9) {
      int z = z0 + g / 3 - 1, y = y0 + g % 3 - 1, xg = xi - 1;
      if ((unsigned)z < 128u && (unsigned)y < 128u && (unsigned)xg < 128u)
        v = src[(z * 128 + y) * 128 + xg];
    }
    dst[xi * PKG + g] = v;
  }
  __syncthreads();

  f32x4 acc[2];
#pragma unroll
  for (int nt = 0; nt < 2; ++nt) acc[nt] = (f32x4){0.f, 0.f, 0.f, 0.f};

  const int n = lane & 15;
  const int q = lane >> 4;
  const int xbase = wv * 32 + n;

#pragma unroll
  for (int dx = 0; dx < 3; ++dx) {
#pragma unroll
    for (int s = 0; s < 3; ++s) {
      bf16x8 bfr[2];
#pragma unroll
      for (int nt = 0; nt < 2; ++nt) {
        int off = ((xbase + nt * 16 + dx) * PKG + (s * 4 + q)) * 8;
        bfr[nt] = *(const bf16x8*)&T[off];
      }
#pragma unroll
      for (int nt = 0; nt < 2; ++nt)
        acc[nt] = __builtin_amdgcn_mfma_f32_16x16x32_bf16(
            wf[dx][s], bfr[nt], acc[nt], 0, 0, 0);
    }
  }

  const int voxrow = (z0 * 128 + y0) * 128;
  if (q < 2) {
#pragma unroll
    for (int nt = 0; nt < 2; ++nt) {
      const int vox = voxrow + wv * 32 + nt * 16 + n;
      ushort4 o;
      o.x = f2b(fmaxf(acc[nt][0] + b1[q * 4 + 0], 0.f));
      o.y = f2b(fmaxf(acc[nt][1] + b1[q * 4 + 1], 0.f));
      o.z = f2b(fmaxf(acc[nt][2] + b1[q * 4 + 2], 0.f));
      o.w = f2b(fmaxf(acc[nt][3] + b1[q * 4 + 3], 0.f));
      *(ushort4*)(hb + (size_t)vox * 8 + q * 4) = o;
    }
  }
}

// ---------------------------------------------------------------------------
// Kernel 2: conv3d(h, w2) (8 -> 27) + fused L1 norm, implicit-GEMM MFMA.
// ---------------------------------------------------------------------------
__global__ __launch_bounds__(256) void k_conv2(
    const unsigned short* __restrict__ hb,
    const unsigned short* __restrict__ Wpack2,
    unsigned short* __restrict__ wn) {
  __shared__ __align__(16) unsigned short T[XT * PKG * 8];
  const int tid  = threadIdx.x;
  const int lane = tid & 63;
  const int wv   = tid >> 6;
  const int z0 = blockIdx.x >> 7;
  const int y0 = blockIdx.x & 127;

  bf16x8 wf[3][3][2];
  {
    const bf16x8* wp = (const bf16x8*)Wpack2;
#pragma unroll
    for (int dx = 0; dx < 3; ++dx)
#pragma unroll
      for (int s = 0; s < 3; ++s)
#pragma unroll
        for (int mt = 0; mt < 2; ++mt)
          wf[dx][s][mt] = wp[((dx * 3 + s) * 2 + mt) * 64 + lane];
  }

  const uint4* src = (const uint4*)hb;
  uint4* dst = (uint4*)T;
#pragma unroll 1
  for (int c = tid; c < 12 * XT; c += 256) {
    int g  = c / XT;
    int xi = c - g * XT;
    uint4 v = make_uint4(0u, 0u, 0u, 0u);
    if (g < 9) {
      int z = z0 + g / 3 - 1, y = y0 + g % 3 - 1, xg = xi - 1;
      if ((unsigned)z < 128u && (unsigned)y < 128u && (unsigned)xg < 128u)
        v = src[(z * 128 + y) * 128 + xg];
    }
    dst[xi * PKG + g] = v;
  }
  __syncthreads();

  f32x4 acc[2][2];  // [nt][mt]
#pragma unroll
  for (int nt = 0; nt < 2; ++nt)
#pragma unroll
    for (int mt = 0; mt < 2; ++mt) acc[nt][mt] = (f32x4){0.f, 0.f, 0.f, 0.f};

  const int n = lane & 15;
  const int q = lane >> 4;
  const int xbase = wv * 32 + n;

#pragma unroll
  for (int dx = 0; dx < 3; ++dx) {
#pragma unroll
    for (int s = 0; s < 3; ++s) {
      bf16x8 bfr[2];
#pragma unroll
      for (int nt = 0; nt < 2; ++nt) {
        int off = ((xbase + nt * 16 + dx) * PKG + (s * 4 + q)) * 8;
        bfr[nt] = *(const bf16x8*)&T[off];
      }
#pragma unroll
      for (int mt = 0; mt < 2; ++mt)
#pragma unroll
        for (int nt = 0; nt < 2; ++nt)
          acc[nt][mt] = __builtin_amdgcn_mfma_f32_16x16x32_bf16(
              wf[dx][s][mt], bfr[nt], acc[nt][mt], 0, 0, 0);
    }
  }

  const int voxrow = (z0 * 128 + y0) * 128;
#pragma unroll
  for (int nt = 0; nt < 2; ++nt) {
    float ns = 0.f;
#pragma unroll
    for (int r = 0; r < 4; ++r) ns += fabsf(acc[nt][0][r]);
#pragma unroll
    for (int r = 0; r < 4; ++r) {
      int oc = 16 + q * 4 + r;
      ns += (oc < 27) ? fabsf(acc[nt][1][r]) : 0.f;
    }
    ns += __shfl_xor(ns, 16);
    ns += __shfl_xor(ns, 32);
    float sc = 1.f / fmaxf(ns, 1e-12f);
    const int vox = voxrow + wv * 32 + nt * 16 + n;
#pragma unroll
    for (int r = 0; r < 4; ++r) {
      int oc = q * 4 + r;
      wn[(size_t)oc * DHW + vox] = f2b(acc[nt][0][r] * sc);
    }
#pragma unroll
    for (int r = 0; r < 4; ++r) {
      int oc = 16 + q * 4 + r;
      if (oc < 27)
        wn[(size_t)oc * DHW + vox] = f2b(acc[nt][1][r] * sc);
    }
  }
}

// ---------------------------------------------------------------------------
// Kernel 3 (R5 redesign): LDS-tiled adaptive 3x3x3 conv.
// R3/R4 lesson: register prefetch windows get serialized (56 VGPR) or
// spilled (84 VGPR + 214 MiB scratch traffic). Move the window to LDS:
//   - block = 128x * 2y * 2z output tile (512 vox), grid 64*64.
//   - stage 16 input rows (4y*4z) * 130 slots interleaved fp32 -> 66 KiB LDS;
//     16 fully-coalesced 4-KiB row copies, 16 loads in flight per thread.
//   - wave = one output row; lane = 2 voxels; per (dz,dy) group 8 ds_read_b128
//     (~120 cy latency, hidden by 2 blocks/CU) + 3 coalesced u32 weight loads
//     (9-group loop fully unrolled -> all 27 hoisted, static indexing).
//   - x halo = zeroed LDS slots; y/z edges = clamped rows + weight zeroing.
//   - XOR swizzle (off ^ ((off>>7)&7)<<4) on ds_write AND ds_read: every 8
//     lanes tile all 32 banks -> conflict-free.
//   - stores: wave covers a contiguous x row -> interleaved stores are 4 KiB
//     contiguous per wave; planar final stores float2-coalesced. No LDS
//     store-transpose needed.
// LDS 67584 B -> 2 blocks/CU; registers free: __launch_bounds__(256,2).
// ---------------------------------------------------------------------------
__device__ inline int swzb(int off) { return off ^ (((off >> 7) & 7) << 4); }

template <int FINAL>
__global__ __launch_bounds__(256, 2) void k_adapt4(
    const float* __restrict__ in, const unsigned short* __restrict__ wn,
    float* __restrict__ out) {
  __shared__ __align__(16) char S[16 * 4224];
  const int tid = threadIdx.x;
  const int ty = blockIdx.x & 63, tz = blockIdx.x >> 6;
  const int y0 = ty * 2, z0 = tz * 2;

  // ---- stage 16 input rows (z' 0..3, y' 0..3), swizzled ----
  uint4 stg[16];
#pragma unroll
  for (int c = 0; c < 16; ++c) {
    const int zs = min(max(z0 - 1 + (c >> 2), 0), 127);
    const int ys = min(max(y0 - 1 + (c & 3), 0), 127);
    stg[c] = ((const uint4*)(in + (size_t)(zs * 128 + ys) * 1024))[tid];
  }
  {
    const int off = swzb(32 + tid * 16);
#pragma unroll
    for (int c = 0; c < 16; ++c)
      *(uint4*)(S + c * 4224 + off) = stg[c];
  }
  if (tid < 64) {  // zero x-halo slots 0 (x=-1) and 129 (x=128) of each row
    const int row = tid >> 2, part = tid & 3;
    const int off = (part < 2) ? part * 16 : (4128 + (part - 2) * 16);
    *(uint4*)(S + row * 4224 + swzb(off)) = make_uint4(0u, 0u, 0u, 0u);
  }
  __syncthreads();

  // ---- compute: wave = output row (yl, zl); lane = 2 voxels ----
  const int wv = tid >> 6, lane = tid & 63;
  const int zl = wv >> 1, yl = wv & 1;
  const int zout = z0 + zl, yout = y0 + yl;
  const int xg = lane * 2;
  const int vox0 = (zout * 128 + yout) * 128 + xg;

  int soff[4][2];
#pragma unroll
  for (int p = 0; p < 4; ++p)
#pragma unroll
    for (int h = 0; h < 2; ++h)
      soff[p][h] = swzb((xg + p) * 32 + h * 16);

  f32x4 a0A = (f32x4){0.f, 0.f, 0.f, 0.f};
  f32x4 a0B = (f32x4){0.f, 0.f, 0.f, 0.f};
  f32x4 a1A = (f32x4){0.f, 0.f, 0.f, 0.f};
  f32x4 a1B = (f32x4){0.f, 0.f, 0.f, 0.f};

#pragma unroll
  for (int g = 0; g < 9; ++g) {
    const int dzp = g / 3, dyp = g % 3;  // static (full unroll)
    const char* R = S + ((zl + dzp) * 4 + (yl + dyp)) * 4224;
    f32x4 W[4][2];
#pragma unroll
    for (int p = 0; p < 4; ++p)
#pragma unroll
      for (int h = 0; h < 2; ++h)
        W[p][h] = *(const f32x4*)(R + soff[p][h]);
    const bool val = ((unsigned)(zout + dzp - 1) < 128u) &
                     ((unsigned)(yout + dyp - 1) < 128u);
#pragma unroll
    for (int dxi = 0; dxi < 3; ++dxi) {
      const unsigned u =
          *(const unsigned*)(wn + (size_t)(g * 3 + dxi) * DHW + vox0);
      const float wl = val ? b2f((unsigned short)(u & 0xffffu)) : 0.f;
      const float wh = val ? b2f((unsigned short)(u >> 16)) : 0.f;
#pragma unroll
      for (int c = 0; c < 4; ++c) {
        a0A[c] = fmaf(W[dxi][0][c], wl, a0A[c]);
        a0B[c] = fmaf(W[dxi][1][c], wl, a0B[c]);
        a1A[c] = fmaf(W[dxi + 1][0][c], wh, a1A[c]);
        a1B[c] = fmaf(W[dxi + 1][1][c], wh, a1B[c]);
      }
    }
  }

  if (FINAL) {
    // planar fp32 [c][vox] -> d_out; float2 = 2 voxels, lane-coalesced
#pragma unroll
    for (int c = 0; c < 4; ++c) {
      *(float2*)(out + (size_t)c * DHW + vox0) = make_float2(a0A[c], a1A[c]);
      *(float2*)(out + (size_t)(c + 4) * DHW + vox0) =
          make_float2(a0B[c], a1B[c]);
    }
  } else {
    // interleaved fp32 [vox][8]; wave writes 4 KiB contiguous
    f32x4* op = (f32x4*)(out + (size_t)vox0 * 8);
    op[0] = a0A;
    op[1] = a0B;
    op[2] = a1A;
    op[3] = a1B;
  }
}

// ---------------------------------------------------------------------------
extern "C" void kernel_launch(void* const* d_in, const int* in_sizes, int n_in,
                              void* d_out, int out_size, void* d_ws, size_t ws_size,
                              hipStream_t stream) {
  const float* x  = (const float*)d_in[0];
  const float* w1 = (const float*)d_in[1];
  const float* b1 = (const float*)d_in[2];
  const float* w2 = (const float*)d_in[3];
  float* out = (float*)d_out;

  // Workspace (~236 MiB + pads):
  //   [0,   64M): xb(32M)+hb(32M) bf16; reused as ti = ws+256 (64M fp32)
  //   [64M+4K, 172M+4K): wn bf16 planar (27 x DHW)
  //   [172M+12K, 236M+12K): xi fp32 interleaved
  //   then Wpack2, Wpack1.
  char* ws = (char*)d_ws;
  unsigned short* xb = (unsigned short*)ws;
  unsigned short* hb = (unsigned short*)(ws + (size_t)8 * DHW * 2);
  float* ti = (float*)(ws + 256);  // aliases xb+hb (both dead before adapt)
  unsigned short* wn = (unsigned short*)(ws + (size_t)16 * DHW * 2 + 4096);
  float* xi = (float*)(ws + (size_t)16 * DHW * 2 + 4096 +
                       (size_t)27 * DHW * 2 + 8192);
  unsigned short* Wpack2 =
      (unsigned short*)((char*)xi + (size_t)8 * DHW * 4 + 16384);
  unsigned short* Wpack1 = Wpack2 + 9216;

  dim3 blk(256);
  k_prep<<<55, blk, 0, stream>>>(w1, w2, Wpack2, Wpack1, ti, xi);
  k_xpose<<<DHW / 256, blk, 0, stream>>>(x, xb, xi);
  k_conv1m<<<128 * 128, blk, 0, stream>>>(xb, Wpack1, b1, hb);
  k_conv2<<<128 * 128, blk, 0, stream>>>(hb, Wpack2, wn);
  // adaptive ping-pong on interleaved fp32: xi -> ti -> xi -> out (planar)
  k_adapt4<0><<<64 * 64, blk, 0, stream>>>(xi, wn, ti);
  k_adapt4<0><<<64 * 64, blk, 0, stream>>>(ti, wn, xi);
  k_adapt4<1><<<64 * 64, blk, 0, stream>>>(xi, wn, out);
}

// Round 6
// 388.393 us; speedup vs baseline: 1.6474x; 1.0763x over previous
//
#include <hip/hip_runtime.h>
#include <hip/hip_bf16.h>

// Geometry (fixed): B=1, C=8, D=H=W=128.
constexpr int HW2 = 16384;
constexpr int DHW = 2097152;

// MFMA staging: LDS cell = 8 ci (bf16, 16 B) at (g = dz*4+dy group, xi).
// Slot map g -> (dz = g>>2, dy = g&3); dy==3 slots are K-pad zeros.
// Pitch 13 groups (208 B): b128 lane-stride 52 words -> 2-way max (free).
constexpr int PKG = 13;   // groups per xi row (12 slots + 1 pitch pad)
constexpr int XT  = 130;  // staged x extent: x = -1 .. 128

typedef short bf16x8 __attribute__((ext_vector_type(8)));  // 8 bf16 = 4 VGPR
typedef float f32x4  __attribute__((ext_vector_type(4)));

__device__ inline unsigned short f2b(float f) {
  __hip_bfloat16 h = __float2bfloat16(f);
  return *(unsigned short*)&h;
}
__device__ inline float b2f(unsigned short u) {
  __hip_bfloat16 h = *(__hip_bfloat16*)&u;
  return __bfloat162float(h);
}

// ---------------------------------------------------------------------------
// Prep: pack w1/w2 into MFMA A-fragment order, bf16, dx-split.
// Slot g = s*4+q interpreted as (dz = g>>2 = s, dy = g&3 = q); dy==3 -> 0.
// ---------------------------------------------------------------------------
__global__ __launch_bounds__(256) void k_prep(
    const float* __restrict__ w1, const float* __restrict__ w2,
    unsigned short* __restrict__ Wpack2, unsigned short* __restrict__ Wpack1,
    float* __restrict__ g_ti, float* __restrict__ g_xi) {
  int i = blockIdx.x * 256 + threadIdx.x;
  if (i < 9216) {
    int j = i & 7;
    int lane = (i >> 3) & 63;
    int Mt = (i >> 9) & 1;
    int g2 = i >> 10;         // dx*3 + s
    int s = g2 % 3, dx = g2 / 3;
    int oc = Mt * 16 + (lane & 15);
    int kr = s * 32 + (lane >> 4) * 8 + j;
    int ci = kr & 7, g = kr >> 3;          // g = s*4 + q
    float w = 0.f;
    if (oc < 27 && (g & 3) < 3) {
      int dzr = g >> 2, dyr = g & 3;
      w = w2[(oc * 8 + ci) * 27 + dzr * 9 + dyr * 3 + dx];
    }
    Wpack2[i] = f2b(w);
  }
  int jj = i - 9216;
  if (jj >= 0 && jj < 4608) {
    int j = jj & 7;
    int lane = (jj >> 3) & 63;
    int g2 = jj >> 9;         // dx*3 + s
    int s = g2 % 3, dx = g2 / 3;
    int oc = lane & 15;
    int kr = s * 32 + (lane >> 4) * 8 + j;
    int ci = kr & 7, g = kr >> 3;
    float w = 0.f;
    if (oc < 8 && (g & 3) < 3) {
      int dzr = g >> 2, dyr = g & 3;
      w = w1[(oc * 8 + ci) * 27 + dzr * 9 + dyr * 3 + dx];
    }
    Wpack1[jj] = f2b(w);
  }
  int gg = i - 13824;
  if (gg >= 0 && gg < 32) {
    float* p = (gg < 8)  ? (g_ti - 8 + gg)
             : (gg < 16) ? (g_ti + (size_t)8 * DHW + (gg - 8))
             : (gg < 24) ? (g_xi - 8 + (gg - 16))
                         : (g_xi + (size_t)8 * DHW + (gg - 24));
    *p = 0.f;
  }
}

// ---------------------------------------------------------------------------
// Transpose x: [ci][z][y][x] fp32 -> [z][y][x][ci] bf16 (xb, for conv1 MFMA)
//                                 and [z][y][x][ci] fp32 (xi, for adapt pass)
// ---------------------------------------------------------------------------
__global__ __launch_bounds__(256) void k_xpose(
    const float* __restrict__ x, unsigned short* __restrict__ xb,
    float* __restrict__ xi) {
  int idx = blockIdx.x * 256 + threadIdx.x;  // voxel
  float f[8];
  unsigned v[4];
#pragma unroll
  for (int p = 0; p < 4; ++p) {
    f[2 * p]     = x[(size_t)(2 * p) * DHW + idx];
    f[2 * p + 1] = x[(size_t)(2 * p + 1) * DHW + idx];
    unsigned lo = f2b(f[2 * p]);
    unsigned hi = f2b(f[2 * p + 1]);
    v[p] = lo | (hi << 16);
  }
  ((uint4*)xb)[idx] = make_uint4(v[0], v[1], v[2], v[3]);
  float4* xo = (float4*)(xi + (size_t)idx * 8);
  xo[0] = make_float4(f[0], f[1], f[2], f[3]);
  xo[1] = make_float4(f[4], f[5], f[6], f[7]);
}

// ---------------------------------------------------------------------------
// Shared conv staging (R6): batched-MLP, division-free.
//   - 24 threads zero the two always-OOB x-halo columns (xi = 0, 129).
//   - main: thread covers (g = (tid>>7) + 2*it, xi = (tid&127)+1), 6 static
//     iterations; ALL 6 loads issued into sv[] first (adapt4-proven pattern,
//     ~6 outstanding HBM loads/wave), then selected + written to LDS.
// ---------------------------------------------------------------------------
#define STAGE_ROWS(srcp)                                                   \
  {                                                                        \
    if (tid < 24) {                                                        \
      int gh = tid >> 1, xih = (tid & 1) ? 129 : 0;                        \
      dst[xih * PKG + gh] = make_uint4(0u, 0u, 0u, 0u);                    \
    }                                                                      \
    const int gg = tid >> 7;                                               \
    const int xi_ = (tid & 127) + 1;                                       \
    const int xg_ = xi_ - 1;                                               \
    uint4 sv[6];                                                           \
    bool vld[6];                                                           \
    _Pragma("unroll")                                                      \
    for (int it = 0; it < 6; ++it) {                                       \
      const int g = gg + it * 2;                                           \
      const int dz = g >> 2, dy = g & 3;                                   \
      const int z = z0 + dz - 1, y = y0 + dy - 1;                          \
      vld[it] = (dy < 3) & ((unsigned)z < 128u) & ((unsigned)y < 128u);    \
      const int zz = vld[it] ? z : z0, yy = vld[it] ? y : y0;              \
      sv[it] = (srcp)[(zz * 128 + yy) * 128 + xg_];                        \
    }                                                                      \
    _Pragma("unroll")                                                      \
    for (int it = 0; it < 6; ++it) {                                       \
      const int g = gg + it * 2;                                           \
      uint4 v = vld[it] ? sv[it] : make_uint4(0u, 0u, 0u, 0u);             \
      dst[xi_ * PKG + g] = v;                                              \
    }                                                                      \
  }

// ---------------------------------------------------------------------------
// Kernel 1: conv3d(x, w1) + bias + ReLU (8 -> 8), implicit-GEMM MFMA.
// ---------------------------------------------------------------------------
__global__ __launch_bounds__(256) void k_conv1m(
    const unsigned short* __restrict__ xb,
    const unsigned short* __restrict__ Wpack1,
    const float* __restrict__ b1, unsigned short* __restrict__ hb) {
  __shared__ __align__(16) unsigned short T[XT * PKG * 8];
  const int tid  = threadIdx.x;
  const int lane = tid & 63;
  const int wv   = tid >> 6;
  // XCD-chunked bijective swizzle (16384 % 8 == 0): band = 16 z * 128 y.
  const int logical = (blockIdx.x & 7) * 2048 + (blockIdx.x >> 3);
  const int z0 = logical >> 7;
  const int y0 = logical & 127;

  bf16x8 wf[3][3];
  {
    const bf16x8* wp = (const bf16x8*)Wpack1;
#pragma unroll
    for (int dx = 0; dx < 3; ++dx)
#pragma unroll
      for (int s = 0; s < 3; ++s)
        wf[dx][s] = wp[(dx * 3 + s) * 64 + lane];
  }

  const uint4* src = (const uint4*)xb;
  uint4* dst = (uint4*)T;
  STAGE_ROWS(src);
  __syncthreads();

  f32x4 acc[2];
#pragma unroll
  for (int nt = 0; nt < 2; ++nt) acc[nt] = (f32x4){0.f, 0.f, 0.f, 0.f};

  const int n = lane & 15;
  const int q = lane >> 4;
  const int xbase = wv * 32 + n;

#pragma unroll
  for (int dx = 0; dx < 3; ++dx) {
#pragma unroll
    for (int s = 0; s < 3; ++s) {
      bf16x8 bfr[2];
#pragma unroll
      for (int nt = 0; nt < 2; ++nt) {
        int off = ((xbase + nt * 16 + dx) * PKG + (s * 4 + q)) * 8;
        bfr[nt] = *(const bf16x8*)&T[off];
      }
#pragma unroll
      for (int nt = 0; nt < 2; ++nt)
        acc[nt] = __builtin_amdgcn_mfma_f32_16x16x32_bf16(
            wf[dx][s], bfr[nt], acc[nt], 0, 0, 0);
    }
  }

  const int voxrow = (z0 * 128 + y0) * 128;
  if (q < 2) {
#pragma unroll
    for (int nt = 0; nt < 2; ++nt) {
      const int vox = voxrow + wv * 32 + nt * 16 + n;
      ushort4 o;
      o.x = f2b(fmaxf(acc[nt][0] + b1[q * 4 + 0], 0.f));
      o.y = f2b(fmaxf(acc[nt][1] + b1[q * 4 + 1], 0.f));
      o.z = f2b(fmaxf(acc[nt][2] + b1[q * 4 + 2], 0.f));
      o.w = f2b(fmaxf(acc[nt][3] + b1[q * 4 + 3], 0.f));
      *(ushort4*)(hb + (size_t)vox * 8 + q * 4) = o;
    }
  }
}

// ---------------------------------------------------------------------------
// Kernel 2: conv3d(h, w2) (8 -> 27) + fused L1 norm, implicit-GEMM MFMA.
// ---------------------------------------------------------------------------
__global__ __launch_bounds__(256) void k_conv2(
    const unsigned short* __restrict__ hb,
    const unsigned short* __restrict__ Wpack2,
    unsigned short* __restrict__ wn) {
  __shared__ __align__(16) unsigned short T[XT * PKG * 8];
  const int tid  = threadIdx.x;
  const int lane = tid & 63;
  const int wv   = tid >> 6;
  const int logical = (blockIdx.x & 7) * 2048 + (blockIdx.x >> 3);
  const int z0 = logical >> 7;
  const int y0 = logical & 127;

  bf16x8 wf[3][3][2];
  {
    const bf16x8* wp = (const bf16x8*)Wpack2;
#pragma unroll
    for (int dx = 0; dx < 3; ++dx)
#pragma unroll
      for (int s = 0; s < 3; ++s)
#pragma unroll
        for (int mt = 0; mt < 2; ++mt)
          wf[dx][s][mt] = wp[((dx * 3 + s) * 2 + mt) * 64 + lane];
  }

  const uint4* src = (const uint4*)hb;
  uint4* dst = (uint4*)T;
  STAGE_ROWS(src);
  __syncthreads();

  f32x4 acc[2][2];  // [nt][mt]
#pragma unroll
  for (int nt = 0; nt < 2; ++nt)
#pragma unroll
    for (int mt = 0; mt < 2; ++mt) acc[nt][mt] = (f32x4){0.f, 0.f, 0.f, 0.f};

  const int n = lane & 15;
  const int q = lane >> 4;
  const int xbase = wv * 32 + n;

#pragma unroll
  for (int dx = 0; dx < 3; ++dx) {
#pragma unroll
    for (int s = 0; s < 3; ++s) {
      bf16x8 bfr[2];
#pragma unroll
      for (int nt = 0; nt < 2; ++nt) {
        int off = ((xbase + nt * 16 + dx) * PKG + (s * 4 + q)) * 8;
        bfr[nt] = *(const bf16x8*)&T[off];
      }
#pragma unroll
      for (int mt = 0; mt < 2; ++mt)
#pragma unroll
        for (int nt = 0; nt < 2; ++nt)
          acc[nt][mt] = __builtin_amdgcn_mfma_f32_16x16x32_bf16(
              wf[dx][s][mt], bfr[nt], acc[nt][mt], 0, 0, 0);
    }
  }

  const int voxrow = (z0 * 128 + y0) * 128;
#pragma unroll
  for (int nt = 0; nt < 2; ++nt) {
    float ns = 0.f;
#pragma unroll
    for (int r = 0; r < 4; ++r) ns += fabsf(acc[nt][0][r]);
#pragma unroll
    for (int r = 0; r < 4; ++r) {
      int oc = 16 + q * 4 + r;
      ns += (oc < 27) ? fabsf(acc[nt][1][r]) : 0.f;
    }
    ns += __shfl_xor(ns, 16);
    ns += __shfl_xor(ns, 32);
    float sc = 1.f / fmaxf(ns, 1e-12f);
    const int vox = voxrow + wv * 32 + nt * 16 + n;
#pragma unroll
    for (int r = 0; r < 4; ++r) {
      int oc = q * 4 + r;
      wn[(size_t)oc * DHW + vox] = f2b(acc[nt][0][r] * sc);
    }
#pragma unroll
    for (int r = 0; r < 4; ++r) {
      int oc = 16 + q * 4 + r;
      if (oc < 27)
        wn[(size_t)oc * DHW + vox] = f2b(acc[nt][1][r] * sc);
    }
  }
}

// ---------------------------------------------------------------------------
// Kernel 3 (R5-proven): LDS-tiled adaptive 3x3x3 conv + R6 XCD swizzle.
// ---------------------------------------------------------------------------
__device__ inline int swzb(int off) { return off ^ (((off >> 7) & 7) << 4); }

template <int FINAL>
__global__ __launch_bounds__(256, 2) void k_adapt4(
    const float* __restrict__ in, const unsigned short* __restrict__ wn,
    float* __restrict__ out) {
  __shared__ __align__(16) char S[16 * 4224];
  const int tid = threadIdx.x;
  // XCD-chunked bijective swizzle (4096 % 8 == 0): band = 8 tz * 64 ty.
  const int logical = (blockIdx.x & 7) * 512 + (blockIdx.x >> 3);
  const int ty = logical & 63, tz = logical >> 6;
  const int y0 = ty * 2, z0 = tz * 2;

  // ---- stage 16 input rows (z' 0..3, y' 0..3), swizzled ----
  uint4 stg[16];
#pragma unroll
  for (int c = 0; c < 16; ++c) {
    const int zs = min(max(z0 - 1 + (c >> 2), 0), 127);
    const int ys = min(max(y0 - 1 + (c & 3), 0), 127);
    stg[c] = ((const uint4*)(in + (size_t)(zs * 128 + ys) * 1024))[tid];
  }
  {
    const int off = swzb(32 + tid * 16);
#pragma unroll
    for (int c = 0; c < 16; ++c)
      *(uint4*)(S + c * 4224 + off) = stg[c];
  }
  if (tid < 64) {  // zero x-halo slots 0 (x=-1) and 129 (x=128) of each row
    const int row = tid >> 2, part = tid & 3;
    const int off = (part < 2) ? part * 16 : (4128 + (part - 2) * 16);
    *(uint4*)(S + row * 4224 + swzb(off)) = make_uint4(0u, 0u, 0u, 0u);
  }
  __syncthreads();

  // ---- compute: wave = output row (yl, zl); lane = 2 voxels ----
  const int wv = tid >> 6, lane = tid & 63;
  const int zl = wv >> 1, yl = wv & 1;
  const int zout = z0 + zl, yout = y0 + yl;
  const int xg = lane * 2;
  const int vox0 = (zout * 128 + yout) * 128 + xg;

  int soff[4][2];
#pragma unroll
  for (int p = 0; p < 4; ++p)
#pragma unroll
    for (int h = 0; h < 2; ++h)
      soff[p][h] = swzb((xg + p) * 32 + h * 16);

  f32x4 a0A = (f32x4){0.f, 0.f, 0.f, 0.f};
  f32x4 a0B = (f32x4){0.f, 0.f, 0.f, 0.f};
  f32x4 a1A = (f32x4){0.f, 0.f, 0.f, 0.f};
  f32x4 a1B = (f32x4){0.f, 0.f, 0.f, 0.f};

#pragma unroll
  for (int g = 0; g < 9; ++g) {
    const int dzp = g / 3, dyp = g % 3;  // static (full unroll)
    const char* R = S + ((zl + dzp) * 4 + (yl + dyp)) * 4224;
    f32x4 W[4][2];
#pragma unroll
    for (int p = 0; p < 4; ++p)
#pragma unroll
      for (int h = 0; h < 2; ++h)
        W[p][h] = *(const f32x4*)(R + soff[p][h]);
    const bool val = ((unsigned)(zout + dzp - 1) < 128u) &
                     ((unsigned)(yout + dyp - 1) < 128u);
#pragma unroll
    for (int dxi = 0; dxi < 3; ++dxi) {
      const unsigned u =
          *(const unsigned*)(wn + (size_t)(g * 3 + dxi) * DHW + vox0);
      const float wl = val ? b2f((unsigned short)(u & 0xffffu)) : 0.f;
      const float wh = val ? b2f((unsigned short)(u >> 16)) : 0.f;
#pragma unroll
      for (int c = 0; c < 4; ++c) {
        a0A[c] = fmaf(W[dxi][0][c], wl, a0A[c]);
        a0B[c] = fmaf(W[dxi][1][c], wl, a0B[c]);
        a1A[c] = fmaf(W[dxi + 1][0][c], wh, a1A[c]);
        a1B[c] = fmaf(W[dxi + 1][1][c], wh, a1B[c]);
      }
    }
  }

  if (FINAL) {
    // planar fp32 [c][vox] -> d_out; float2 = 2 voxels, lane-coalesced
#pragma unroll
    for (int c = 0; c < 4; ++c) {
      *(float2*)(out + (size_t)c * DHW + vox0) = make_float2(a0A[c], a1A[c]);
      *(float2*)(out + (size_t)(c + 4) * DHW + vox0) =
          make_float2(a0B[c], a1B[c]);
    }
  } else {
    // interleaved fp32 [vox][8]; wave writes 4 KiB contiguous
    f32x4* op = (f32x4*)(out + (size_t)vox0 * 8);
    op[0] = a0A;
    op[1] = a0B;
    op[2] = a1A;
    op[3] = a1B;
  }
}

// ---------------------------------------------------------------------------
extern "C" void kernel_launch(void* const* d_in, const int* in_sizes, int n_in,
                              void* d_out, int out_size, void* d_ws, size_t ws_size,
                              hipStream_t stream) {
  const float* x  = (const float*)d_in[0];
  const float* w1 = (const float*)d_in[1];
  const float* b1 = (const float*)d_in[2];
  const float* w2 = (const float*)d_in[3];
  float* out = (float*)d_out;

  // Workspace (~236 MiB + pads):
  //   [0,   64M): xb(32M)+hb(32M) bf16; reused as ti = ws+256 (64M fp32)
  //   [64M+4K, 172M+4K): wn bf16 planar (27 x DHW)
  //   [172M+12K, 236M+12K): xi fp32 interleaved
  //   then Wpack2, Wpack1.
  char* ws = (char*)d_ws;
  unsigned short* xb = (unsigned short*)ws;
  unsigned short* hb = (unsigned short*)(ws + (size_t)8 * DHW * 2);
  float* ti = (float*)(ws + 256);  // aliases xb+hb (both dead before adapt)
  unsigned short* wn = (unsigned short*)(ws + (size_t)16 * DHW * 2 + 4096);
  float* xi = (float*)(ws + (size_t)16 * DHW * 2 + 4096 +
                       (size_t)27 * DHW * 2 + 8192);
  unsigned short* Wpack2 =
      (unsigned short*)((char*)xi + (size_t)8 * DHW * 4 + 16384);
  unsigned short* Wpack1 = Wpack2 + 9216;

  dim3 blk(256);
  k_prep<<<55, blk, 0, stream>>>(w1, w2, Wpack2, Wpack1, ti, xi);
  k_xpose<<<DHW / 256, blk, 0, stream>>>(x, xb, xi);
  k_conv1m<<<128 * 128, blk, 0, stream>>>(xb, Wpack1, b1, hb);
  k_conv2<<<128 * 128, blk, 0, stream>>>(hb, Wpack2, wn);
  // adaptive ping-pong on interleaved fp32: xi -> ti -> xi -> out (planar)
  k_adapt4<0><<<64 * 64, blk, 0, stream>>>(xi, wn, ti);
  k_adapt4<0><<<64 * 64, blk, 0, stream>>>(ti, wn, xi);
  k_adapt4<1><<<64 * 64, blk, 0, stream>>>(xi, wn, out);
}

// Round 7
// 353.331 us; speedup vs baseline: 1.8109x; 1.0992x over previous
//
#include <hip/hip_runtime.h>
#include <hip/hip_bf16.h>

// Geometry (fixed): B=1, C=8, D=H=W=128.
constexpr int HW2 = 16384;
constexpr int DHW = 2097152;

// MFMA staging: LDS cell = 8 ci (bf16, 16 B) at (slot = dz*4+ry, xi).
// R7: y-pair blocks. Slots 0..11 = dz(0..2) x ry(0..3) real rows
// (y = y0-1 .. y0+2); slot 12 zeroed. Output row r reads slot s*4+q+r:
// q=3 lands on garbage-but-finite data with A-weight 0 (slot 12 zeroed so
// s=2,q=3,r=1 is finite too). Pitch 13 cells (208 B) -> conflict-free-ish.
constexpr int PKG = 13;
constexpr int XT  = 130;  // staged x extent: x = -1 .. 128

typedef short bf16x8 __attribute__((ext_vector_type(8)));  // 8 bf16 = 4 VGPR
typedef float f32x4  __attribute__((ext_vector_type(4)));

__device__ inline unsigned short f2b(float f) {
  __hip_bfloat16 h = __float2bfloat16(f);
  return *(unsigned short*)&h;
}
__device__ inline float b2f(unsigned short u) {
  __hip_bfloat16 h = *(__hip_bfloat16*)&u;
  return __bfloat162float(h);
}

// ---------------------------------------------------------------------------
// Prep: pack w1/w2 into MFMA A-fragment order, bf16, dx-split.
// Slot g = s*4+q interpreted as (dz = g>>2 = s, dy = g&3 = q); dy==3 -> 0.
// ---------------------------------------------------------------------------
__global__ __launch_bounds__(256) void k_prep(
    const float* __restrict__ w1, const float* __restrict__ w2,
    unsigned short* __restrict__ Wpack2, unsigned short* __restrict__ Wpack1,
    float* __restrict__ g_ti, float* __restrict__ g_xi) {
  int i = blockIdx.x * 256 + threadIdx.x;
  if (i < 9216) {
    int j = i & 7;
    int lane = (i >> 3) & 63;
    int Mt = (i >> 9) & 1;
    int g2 = i >> 10;         // dx*3 + s
    int s = g2 % 3, dx = g2 / 3;
    int oc = Mt * 16 + (lane & 15);
    int kr = s * 32 + (lane >> 4) * 8 + j;
    int ci = kr & 7, g = kr >> 3;          // g = s*4 + q
    float w = 0.f;
    if (oc < 27 && (g & 3) < 3) {
      int dzr = g >> 2, dyr = g & 3;
      w = w2[(oc * 8 + ci) * 27 + dzr * 9 + dyr * 3 + dx];
    }
    Wpack2[i] = f2b(w);
  }
  int jj = i - 9216;
  if (jj >= 0 && jj < 4608) {
    int j = jj & 7;
    int lane = (jj >> 3) & 63;
    int g2 = jj >> 9;         // dx*3 + s
    int s = g2 % 3, dx = g2 / 3;
    int oc = lane & 15;
    int kr = s * 32 + (lane >> 4) * 8 + j;
    int ci = kr & 7, g = kr >> 3;
    float w = 0.f;
    if (oc < 8 && (g & 3) < 3) {
      int dzr = g >> 2, dyr = g & 3;
      w = w1[(oc * 8 + ci) * 27 + dzr * 9 + dyr * 3 + dx];
    }
    Wpack1[jj] = f2b(w);
  }
  int gg = i - 13824;
  if (gg >= 0 && gg < 32) {
    float* p = (gg < 8)  ? (g_ti - 8 + gg)
             : (gg < 16) ? (g_ti + (size_t)8 * DHW + (gg - 8))
             : (gg < 24) ? (g_xi - 8 + (gg - 16))
                         : (g_xi + (size_t)8 * DHW + (gg - 24));
    *p = 0.f;
  }
}

// ---------------------------------------------------------------------------
// Transpose x: [ci][z][y][x] fp32 -> [z][y][x][ci] bf16 (xb, for conv1 MFMA)
//                                 and [z][y][x][ci] fp32 (xi, for adapt pass)
// ---------------------------------------------------------------------------
__global__ __launch_bounds__(256) void k_xpose(
    const float* __restrict__ x, unsigned short* __restrict__ xb,
    float* __restrict__ xi) {
  int idx = blockIdx.x * 256 + threadIdx.x;  // voxel
  float f[8];
  unsigned v[4];
#pragma unroll
  for (int p = 0; p < 4; ++p) {
    f[2 * p]     = x[(size_t)(2 * p) * DHW + idx];
    f[2 * p + 1] = x[(size_t)(2 * p + 1) * DHW + idx];
    unsigned lo = f2b(f[2 * p]);
    unsigned hi = f2b(f[2 * p + 1]);
    v[p] = lo | (hi << 16);
  }
  ((uint4*)xb)[idx] = make_uint4(v[0], v[1], v[2], v[3]);
  float4* xo = (float4*)(xi + (size_t)idx * 8);
  xo[0] = make_float4(f[0], f[1], f[2], f[3]);
  xo[1] = make_float4(f[4], f[5], f[6], f[7]);
}

// ---------------------------------------------------------------------------
// Shared conv staging (R7 y-pair): 12 real rows (dz 0..2 x ry 0..3),
// batched-MLP (6 loads in flight), division-free. Zero tasks: slot 12 for
// all 130 xi + x-halo columns (xi 0,129) for slots 0..11.
// ---------------------------------------------------------------------------
#define STAGE_ROWS2(srcp)                                                  \
  {                                                                        \
    if (tid < 154) {                                                       \
      if (tid < 130) {                                                     \
        dst[tid * PKG + 12] = make_uint4(0u, 0u, 0u, 0u);                  \
      } else {                                                             \
        int k = tid - 130;                                                 \
        int sl = k >> 1, xih = (k & 1) ? 129 : 0;                          \
        dst[xih * PKG + sl] = make_uint4(0u, 0u, 0u, 0u);                  \
      }                                                                    \
    }                                                                      \
    const int gg = tid >> 7;                                               \
    const int xi_ = (tid & 127) + 1;                                       \
    const int xg_ = xi_ - 1;                                               \
    uint4 sv[6];                                                           \
    bool vld[6];                                                           \
    _Pragma("unroll")                                                      \
    for (int it = 0; it < 6; ++it) {                                       \
      const int g = gg + it * 2;                                           \
      const int dz = g >> 2, ry = g & 3;                                   \
      const int z = z0 + dz - 1, y = y0 + ry - 1;                          \
      vld[it] = ((unsigned)z < 128u) & ((unsigned)y < 128u);               \
      const int zz = vld[it] ? z : z0, yy = vld[it] ? y : y0;              \
      sv[it] = (srcp)[(zz * 128 + yy) * 128 + xg_];                        \
    }                                                                      \
    _Pragma("unroll")                                                      \
    for (int it = 0; it < 6; ++it) {                                       \
      const int g = gg + it * 2;                                           \
      uint4 v = vld[it] ? sv[it] : make_uint4(0u, 0u, 0u, 0u);             \
      dst[xi_ * PKG + g] = v;                                              \
    }                                                                      \
  }

// ---------------------------------------------------------------------------
// Kernel 1: conv3d(x, w1) + bias + ReLU (8 -> 8), implicit-GEMM MFMA.
// y-pair per block; grid 128 z * 64 ypairs = 8192.
// ---------------------------------------------------------------------------
__global__ __launch_bounds__(256, 3) void k_conv1m(
    const unsigned short* __restrict__ xb,
    const unsigned short* __restrict__ Wpack1,
    const float* __restrict__ b1, unsigned short* __restrict__ hb) {
  __shared__ __align__(16) unsigned short T[XT * PKG * 8];
  const int tid  = threadIdx.x;
  const int lane = tid & 63;
  const int wv   = tid >> 6;
  // XCD-chunked bijective swizzle (8192 % 8 == 0), chunk 1024.
  const int logical = (blockIdx.x & 7) * 1024 + (blockIdx.x >> 3);
  const int z0 = logical >> 6;
  const int y0 = (logical & 63) * 2;

  bf16x8 wf[3][3];
  {
    const bf16x8* wp = (const bf16x8*)Wpack1;
#pragma unroll
    for (int dx = 0; dx < 3; ++dx)
#pragma unroll
      for (int s = 0; s < 3; ++s)
        wf[dx][s] = wp[(dx * 3 + s) * 64 + lane];
  }

  const uint4* src = (const uint4*)xb;
  uint4* dst = (uint4*)T;
  STAGE_ROWS2(src);
  __syncthreads();

  f32x4 acc[2][2];  // [r][nt]
#pragma unroll
  for (int r = 0; r < 2; ++r)
#pragma unroll
    for (int nt = 0; nt < 2; ++nt) acc[r][nt] = (f32x4){0.f, 0.f, 0.f, 0.f};

  const int n = lane & 15;
  const int q = lane >> 4;
  const int xbase = wv * 32 + n;

#pragma unroll
  for (int dx = 0; dx < 3; ++dx) {
#pragma unroll
    for (int s = 0; s < 3; ++s) {
      bf16x8 bfr[2][2];
#pragma unroll
      for (int r = 0; r < 2; ++r)
#pragma unroll
        for (int nt = 0; nt < 2; ++nt) {
          int off = ((xbase + nt * 16 + dx) * PKG + (s * 4 + q + r)) * 8;
          bfr[r][nt] = *(const bf16x8*)&T[off];
        }
#pragma unroll
      for (int r = 0; r < 2; ++r)
#pragma unroll
        for (int nt = 0; nt < 2; ++nt)
          acc[r][nt] = __builtin_amdgcn_mfma_f32_16x16x32_bf16(
              wf[dx][s], bfr[r][nt], acc[r][nt], 0, 0, 0);
    }
  }

  if (q < 2) {
#pragma unroll
    for (int r = 0; r < 2; ++r) {
      const int voxrow = (z0 * 128 + y0 + r) * 128;
#pragma unroll
      for (int nt = 0; nt < 2; ++nt) {
        const int vox = voxrow + wv * 32 + nt * 16 + n;
        ushort4 o;
        o.x = f2b(fmaxf(acc[r][nt][0] + b1[q * 4 + 0], 0.f));
        o.y = f2b(fmaxf(acc[r][nt][1] + b1[q * 4 + 1], 0.f));
        o.z = f2b(fmaxf(acc[r][nt][2] + b1[q * 4 + 2], 0.f));
        o.w = f2b(fmaxf(acc[r][nt][3] + b1[q * 4 + 3], 0.f));
        *(ushort4*)(hb + (size_t)vox * 8 + q * 4) = o;
      }
    }
  }
}

// ---------------------------------------------------------------------------
// Kernel 2: conv3d(h, w2) (8 -> 27) + fused L1 norm, implicit-GEMM MFMA.
// y-pair per block; grid 8192.
// ---------------------------------------------------------------------------
__global__ __launch_bounds__(256, 2) void k_conv2(
    const unsigned short* __restrict__ hb,
    const unsigned short* __restrict__ Wpack2,
    unsigned short* __restrict__ wn) {
  __shared__ __align__(16) unsigned short T[XT * PKG * 8];
  const int tid  = threadIdx.x;
  const int lane = tid & 63;
  const int wv   = tid >> 6;
  const int logical = (blockIdx.x & 7) * 1024 + (blockIdx.x >> 3);
  const int z0 = logical >> 6;
  const int y0 = (logical & 63) * 2;

  bf16x8 wf[3][3][2];
  {
    const bf16x8* wp = (const bf16x8*)Wpack2;
#pragma unroll
    for (int dx = 0; dx < 3; ++dx)
#pragma unroll
      for (int s = 0; s < 3; ++s)
#pragma unroll
        for (int mt = 0; mt < 2; ++mt)
          wf[dx][s][mt] = wp[((dx * 3 + s) * 2 + mt) * 64 + lane];
  }

  const uint4* src = (const uint4*)hb;
  uint4* dst = (uint4*)T;
  STAGE_ROWS2(src);
  __syncthreads();

  f32x4 acc[2][2][2];  // [r][nt][mt]
#pragma unroll
  for (int r = 0; r < 2; ++r)
#pragma unroll
    for (int nt = 0; nt < 2; ++nt)
#pragma unroll
      for (int mt = 0; mt < 2; ++mt)
        acc[r][nt][mt] = (f32x4){0.f, 0.f, 0.f, 0.f};

  const int n = lane & 15;
  const int q = lane >> 4;
  const int xbase = wv * 32 + n;

#pragma unroll
  for (int dx = 0; dx < 3; ++dx) {
#pragma unroll
    for (int s = 0; s < 3; ++s) {
      bf16x8 bfr[2][2];
#pragma unroll
      for (int r = 0; r < 2; ++r)
#pragma unroll
        for (int nt = 0; nt < 2; ++nt) {
          int off = ((xbase + nt * 16 + dx) * PKG + (s * 4 + q + r)) * 8;
          bfr[r][nt] = *(const bf16x8*)&T[off];
        }
#pragma unroll
      for (int r = 0; r < 2; ++r)
#pragma unroll
        for (int mt = 0; mt < 2; ++mt)
#pragma unroll
          for (int nt = 0; nt < 2; ++nt)
            acc[r][nt][mt] = __builtin_amdgcn_mfma_f32_16x16x32_bf16(
                wf[dx][s][mt], bfr[r][nt], acc[r][nt][mt], 0, 0, 0);
    }
  }

#pragma unroll
  for (int r = 0; r < 2; ++r) {
    const int voxrow = (z0 * 128 + y0 + r) * 128;
#pragma unroll
    for (int nt = 0; nt < 2; ++nt) {
      float ns = 0.f;
#pragma unroll
      for (int rr = 0; rr < 4; ++rr) ns += fabsf(acc[r][nt][0][rr]);
#pragma unroll
      for (int rr = 0; rr < 4; ++rr) {
        int oc = 16 + q * 4 + rr;
        ns += (oc < 27) ? fabsf(acc[r][nt][1][rr]) : 0.f;
      }
      ns += __shfl_xor(ns, 16);
      ns += __shfl_xor(ns, 32);
      float sc = 1.f / fmaxf(ns, 1e-12f);
      const int vox = voxrow + wv * 32 + nt * 16 + n;
#pragma unroll
      for (int rr = 0; rr < 4; ++rr) {
        int oc = q * 4 + rr;
        wn[(size_t)oc * DHW + vox] = f2b(acc[r][nt][0][rr] * sc);
      }
#pragma unroll
      for (int rr = 0; rr < 4; ++rr) {
        int oc = 16 + q * 4 + rr;
        if (oc < 27)
          wn[(size_t)oc * DHW + vox] = f2b(acc[r][nt][1][rr] * sc);
      }
    }
  }
}

// ---------------------------------------------------------------------------
// Kernel 3 (R5-proven + R7 wn-prefetch): LDS-tiled adaptive 3x3x3 conv.
// All 27 per-voxel weight words are loaded into registers BEFORE the LDS
// staging writes + barrier, so their HBM latency hides under staging; the
// g-loop is then pure LDS+VALU (R6 theory: g-loop wn loads were the
// dominant serial latency at 2 waves/SIMD).
// ---------------------------------------------------------------------------
__device__ inline int swzb(int off) { return off ^ (((off >> 7) & 7) << 4); }

template <int FINAL>
__global__ __launch_bounds__(256, 2) void k_adapt4(
    const float* __restrict__ in, const unsigned short* __restrict__ wn,
    float* __restrict__ out) {
  __shared__ __align__(16) char S[16 * 4224];
  const int tid = threadIdx.x;
  // XCD-chunked bijective swizzle (4096 % 8 == 0): chunk 512.
  const int logical = (blockIdx.x & 7) * 512 + (blockIdx.x >> 3);
  const int ty = logical & 63, tz = logical >> 6;
  const int y0 = ty * 2, z0 = tz * 2;

  // compute-role indices (needed early for wn prefetch)
  const int wv = tid >> 6, lane = tid & 63;
  const int zl = wv >> 1, yl = wv & 1;
  const int zout = z0 + zl, yout = y0 + yl;
  const int xg = lane * 2;
  const int vox0 = (zout * 128 + yout) * 128 + xg;

  // ---- issue staging loads (16 rows) ----
  uint4 stg[16];
#pragma unroll
  for (int c = 0; c < 16; ++c) {
    const int zs = min(max(z0 - 1 + (c >> 2), 0), 127);
    const int ys = min(max(y0 - 1 + (c & 3), 0), 127);
    stg[c] = ((const uint4*)(in + (size_t)(zs * 128 + ys) * 1024))[tid];
  }

  // ---- issue ALL 27 wn loads (latency hidden under staging + barrier) ----
  unsigned wnv[27];
#pragma unroll
  for (int k = 0; k < 27; ++k)
    wnv[k] = *(const unsigned*)(wn + (size_t)k * DHW + vox0);

  // ---- LDS staging writes, swizzled ----
  {
    const int off = swzb(32 + tid * 16);
#pragma unroll
    for (int c = 0; c < 16; ++c)
      *(uint4*)(S + c * 4224 + off) = stg[c];
  }
  if (tid < 64) {  // zero x-halo slots 0 (x=-1) and 129 (x=128) of each row
    const int row = tid >> 2, part = tid & 3;
    const int off = (part < 2) ? part * 16 : (4128 + (part - 2) * 16);
    *(uint4*)(S + row * 4224 + swzb(off)) = make_uint4(0u, 0u, 0u, 0u);
  }
  __syncthreads();

  int soff[4][2];
#pragma unroll
  for (int p = 0; p < 4; ++p)
#pragma unroll
    for (int h = 0; h < 2; ++h)
      soff[p][h] = swzb((xg + p) * 32 + h * 16);

  f32x4 a0A = (f32x4){0.f, 0.f, 0.f, 0.f};
  f32x4 a0B = (f32x4){0.f, 0.f, 0.f, 0.f};
  f32x4 a1A = (f32x4){0.f, 0.f, 0.f, 0.f};
  f32x4 a1B = (f32x4){0.f, 0.f, 0.f, 0.f};

#pragma unroll
  for (int g = 0; g < 9; ++g) {
    const int dzp = g / 3, dyp = g % 3;  // static (full unroll)
    const char* R = S + ((zl + dzp) * 4 + (yl + dyp)) * 4224;
    f32x4 W[4][2];
#pragma unroll
    for (int p = 0; p < 4; ++p)
#pragma unroll
      for (int h = 0; h < 2; ++h)
        W[p][h] = *(const f32x4*)(R + soff[p][h]);
    const bool val = ((unsigned)(zout + dzp - 1) < 128u) &
                     ((unsigned)(yout + dyp - 1) < 128u);
#pragma unroll
    for (int dxi = 0; dxi < 3; ++dxi) {
      const unsigned u = wnv[g * 3 + dxi];
      const float wl = val ? b2f((unsigned short)(u & 0xffffu)) : 0.f;
      const float wh = val ? b2f((unsigned short)(u >> 16)) : 0.f;
#pragma unroll
      for (int c = 0; c < 4; ++c) {
        a0A[c] = fmaf(W[dxi][0][c], wl, a0A[c]);
        a0B[c] = fmaf(W[dxi][1][c], wl, a0B[c]);
        a1A[c] = fmaf(W[dxi + 1][0][c], wh, a1A[c]);
        a1B[c] = fmaf(W[dxi + 1][1][c], wh, a1B[c]);
      }
    }
  }

  if (FINAL) {
    // planar fp32 [c][vox] -> d_out; float2 = 2 voxels, lane-coalesced
#pragma unroll
    for (int c = 0; c < 4; ++c) {
      *(float2*)(out + (size_t)c * DHW + vox0) = make_float2(a0A[c], a1A[c]);
      *(float2*)(out + (size_t)(c + 4) * DHW + vox0) =
          make_float2(a0B[c], a1B[c]);
    }
  } else {
    // interleaved fp32 [vox][8]; wave writes 4 KiB contiguous
    f32x4* op = (f32x4*)(out + (size_t)vox0 * 8);
    op[0] = a0A;
    op[1] = a0B;
    op[2] = a1A;
    op[3] = a1B;
  }
}

// ---------------------------------------------------------------------------
extern "C" void kernel_launch(void* const* d_in, const int* in_sizes, int n_in,
                              void* d_out, int out_size, void* d_ws, size_t ws_size,
                              hipStream_t stream) {
  const float* x  = (const float*)d_in[0];
  const float* w1 = (const float*)d_in[1];
  const float* b1 = (const float*)d_in[2];
  const float* w2 = (const float*)d_in[3];
  float* out = (float*)d_out;

  // Workspace (~236 MiB + pads):
  //   [0,   64M): xb(32M)+hb(32M) bf16; reused as ti = ws+256 (64M fp32)
  //   [64M+4K, 172M+4K): wn bf16 planar (27 x DHW)
  //   [172M+12K, 236M+12K): xi fp32 interleaved
  //   then Wpack2, Wpack1.
  char* ws = (char*)d_ws;
  unsigned short* xb = (unsigned short*)ws;
  unsigned short* hb = (unsigned short*)(ws + (size_t)8 * DHW * 2);
  float* ti = (float*)(ws + 256);  // aliases xb+hb (both dead before adapt)
  unsigned short* wn = (unsigned short*)(ws + (size_t)16 * DHW * 2 + 4096);
  float* xi = (float*)(ws + (size_t)16 * DHW * 2 + 4096 +
                       (size_t)27 * DHW * 2 + 8192);
  unsigned short* Wpack2 =
      (unsigned short*)((char*)xi + (size_t)8 * DHW * 4 + 16384);
  unsigned short* Wpack1 = Wpack2 + 9216;

  dim3 blk(256);
  k_prep<<<55, blk, 0, stream>>>(w1, w2, Wpack2, Wpack1, ti, xi);
  k_xpose<<<DHW / 256, blk, 0, stream>>>(x, xb, xi);
  k_conv1m<<<128 * 64, blk, 0, stream>>>(xb, Wpack1, b1, hb);
  k_conv2<<<128 * 64, blk, 0, stream>>>(hb, Wpack2, wn);
  // adaptive ping-pong on interleaved fp32: xi -> ti -> xi -> out (planar)
  k_adapt4<0><<<64 * 64, blk, 0, stream>>>(xi, wn, ti);
  k_adapt4<0><<<64 * 64, blk, 0, stream>>>(ti, wn, xi);
  k_adapt4<1><<<64 * 64, blk, 0, stream>>>(xi, wn, out);
}